// Round 11
// baseline (288.394 us; speedup 1.0000x reference)
//
#include <hip/hip_runtime.h>
#include <stdint.h>

#define N_PTS 32768
#define M_CENT 1024
#define B_SZ 4
#define NS 32
#define NR 64
#define P_TOT (B_SZ * NS * M_CENT) /* 131072 */

// spatial grid: cell 0.11 > radius 0.1 => +/-1-cell window provably covers
#define GT 29
#define GP 58
#define NCELL (GT * GP) /* 1682 */
#define INVF (1.0f / 0.11f)
#define CAPW 320

__device__ __forceinline__ int cell_t(float t) {
  return min(GT - 1, (int)(t * INVF));
}
__device__ __forceinline__ int cell_p(float p) {
  return min(GP - 1, (int)(p * INVF));
}

// ---------------- threefry2x32 (JAX partitionable mode) ----------------
struct Key2 { uint32_t a, b; };

__device__ __forceinline__ uint32_t rotl32(uint32_t v, uint32_t r) {
  return (v << r) | (v >> (32u - r));
}

__device__ __forceinline__ void tf2x32(uint32_t k0, uint32_t k1,
                                       uint32_t& x0, uint32_t& x1) {
  uint32_t ks0 = k0, ks1 = k1, ks2 = k0 ^ k1 ^ 0x1BD11BDAu;
  x0 += ks0; x1 += ks1;
#define TF_ROUND(r) { x0 += x1; x1 = rotl32(x1, r); x1 ^= x0; }
  TF_ROUND(13u) TF_ROUND(15u) TF_ROUND(26u) TF_ROUND(6u)
  x0 += ks1; x1 += ks2 + 1u;
  TF_ROUND(17u) TF_ROUND(29u) TF_ROUND(16u) TF_ROUND(24u)
  x0 += ks2; x1 += ks0 + 2u;
  TF_ROUND(13u) TF_ROUND(15u) TF_ROUND(26u) TF_ROUND(6u)
  x0 += ks0; x1 += ks1 + 3u;
  TF_ROUND(17u) TF_ROUND(29u) TF_ROUND(16u) TF_ROUND(24u)
  x0 += ks1; x1 += ks2 + 4u;
  TF_ROUND(13u) TF_ROUND(15u) TF_ROUND(26u) TF_ROUND(6u)
  x0 += ks2; x1 += ks0 + 5u;
#undef TF_ROUND
}

__device__ __forceinline__ Key2 tf_block(Key2 k, uint32_t hi, uint32_t lo) {
  uint32_t x0 = hi, x1 = lo;
  tf2x32(k.a, k.b, x0, x1);
  Key2 r; r.a = x0; r.b = x1; return r;
}

// -------- prep: perm bits + bucket hist (j<32768) and cell hist (all j) --------
__global__ __launch_bounds__(256) void prep_kernel(const float* __restrict__ theta,
                                                   const float* __restrict__ phi,
                                                   uint32_t* __restrict__ bits1,
                                                   uint32_t* __restrict__ bits2,
                                                   int* __restrict__ hist1,
                                                   int* __restrict__ hist2,
                                                   int* __restrict__ cellcnt) {
  int j = blockIdx.x * 256 + threadIdx.x;        // 0 .. 131071
  int b = j >> 15;
  float t = theta[j], p = phi[j];
  atomicAdd(&cellcnt[b * NCELL + cell_t(t) * GP + cell_p(p)], 1);
  if (j < N_PTS) {
    Key2 root; root.a = 0u; root.b = 42u;        // jax.random.key(42)
    Key2 k1   = tf_block(root, 0u, 0u);          // split(key)[0] -> permutation key
    Key2 keyA = tf_block(k1, 0u, 0u);
    Key2 sub1 = tf_block(k1, 0u, 1u);
    Key2 sub2 = tf_block(keyA, 0u, 1u);
    Key2 r1 = tf_block(sub1, 0u, (uint32_t)j);
    Key2 r2 = tf_block(sub2, 0u, (uint32_t)j);
    uint32_t v1 = r1.a ^ r1.b, v2 = r2.a ^ r2.b;
    bits1[j] = v1; bits2[j] = v2;
    atomicAdd(&hist1[v1 >> 16], 1);
    atomicAdd(&hist2[v2 >> 16], 1);
  }
}

// -------- feat transpose: [B][16][N] -> [B][N][16] (coalesced both sides) --------
__global__ __launch_bounds__(256) void transpose_kernel(const float* __restrict__ feat,
                                                        float* __restrict__ featT) {
  __shared__ float lds[16][65];                  // 65: conflict-free both phases
  int b = blockIdx.y;
  int n0 = blockIdx.x * 64;
  int tid = threadIdx.x;
#pragma unroll
  for (int k = 0; k < 4; ++k) {
    int v = tid + k * 256;                       // 0..1023
    int c = v >> 6, no = v & 63;
    lds[c][no] = feat[((size_t)(b * 16 + c) << 15) + n0 + no];
  }
  __syncthreads();
#pragma unroll
  for (int k = 0; k < 4; ++k) {
    int v = tid + k * 256;
    int no = v >> 4, c = v & 15;
    featT[((size_t)(b << 15) + n0 + no) * 16 + c] = lds[c][no];
  }
}

// -------- fused scans: blocks 0-1 = bucket group sums; blocks 2-5 = cell scans --------
__global__ __launch_bounds__(256) void scans_kernel(const int* __restrict__ hist1,
                                                    const int* __restrict__ hist2,
                                                    int* __restrict__ gbase1,
                                                    int* __restrict__ gbase2,
                                                    const int* __restrict__ cellcnt,
                                                    int* __restrict__ cellpre,
                                                    int* __restrict__ cellcur) {
  __shared__ int s[256];
  int t = threadIdx.x;
  if (blockIdx.x < 2) {
    const int* hist = blockIdx.x == 0 ? hist1 : hist2;
    int* gbase = blockIdx.x == 0 ? gbase1 : gbase2;
    int sum = 0;
    for (int i = 0; i < 256; ++i) sum += hist[t * 256 + i];
    s[t] = sum;
    __syncthreads();
    if (t == 0) {
      int run = 0;
      for (int i = 0; i < 256; ++i) { int v = s[i]; s[i] = run; run += v; }
    }
    __syncthreads();
    gbase[t] = s[t];
  } else {
    int b = blockIdx.x - 2;
    const int* cnt = cellcnt + b * NCELL;
    int i0 = t * 7, i1 = min(i0 + 7, NCELL);
    int sum = 0;
    for (int i = i0; i < i1; ++i) sum += cnt[i];
    s[t] = sum;
    __syncthreads();
    for (int off = 1; off < 256; off <<= 1) {
      int v = (t >= off) ? s[t - off] : 0;
      __syncthreads();
      s[t] += v;
      __syncthreads();
    }
    int run = (t == 0) ? 0 : s[t - 1];
    for (int i = i0; i < i1; ++i) {
      cellpre[b * NCELL + i] = run;
      cellcur[b * NCELL + i] = run;
      run += cnt[i];
    }
  }
}

__global__ __launch_bounds__(256) void bucket_scan_kernel(const int* __restrict__ hist1,
                                                          const int* __restrict__ hist2,
                                                          const int* __restrict__ gbase1,
                                                          const int* __restrict__ gbase2,
                                                          int* __restrict__ prefix1,
                                                          int* __restrict__ prefix2,
                                                          int* __restrict__ cursor1,
                                                          int* __restrict__ cursor2) {
  __shared__ int s[256];
  const int* hist = blockIdx.y == 0 ? hist1 : hist2;
  const int* gbase = blockIdx.y == 0 ? gbase1 : gbase2;
  int* prefix = blockIdx.y == 0 ? prefix1 : prefix2;
  int* cursor = blockIdx.y == 0 ? cursor1 : cursor2;
  int g = blockIdx.x, t = threadIdx.x;
  int idx = g * 256 + t;
  int orig = hist[idx];
  s[t] = orig;
  __syncthreads();
  for (int off = 1; off < 256; off <<= 1) {
    int v = (t >= off) ? s[t - off] : 0;
    __syncthreads();
    s[t] += v;
    __syncthreads();
  }
  int pref = gbase[g] + s[t] - orig;
  prefix[idx] = pref;
  cursor[idx] = pref;
}

// -------- fused scatters: cell scatter (all j, packed float4) + bucket scatter (j<32768) --------
__global__ __launch_bounds__(256) void scatter_kernel(const float* __restrict__ theta,
                                                      const float* __restrict__ phi,
                                                      int* __restrict__ cellcur,
                                                      float4* __restrict__ pts4,
                                                      const uint32_t* __restrict__ bits1,
                                                      const uint32_t* __restrict__ bits2,
                                                      int* __restrict__ cursor1,
                                                      int* __restrict__ cursor2,
                                                      int* __restrict__ sorted1,
                                                      int* __restrict__ sorted2) {
  int j = blockIdx.x * 256 + threadIdx.x;
  int b = j >> 15, n = j & (N_PTS - 1);
  float t = theta[j], p = phi[j];
  int cell = b * NCELL + cell_t(t) * GP + cell_p(p);
  int pos = atomicAdd(&cellcur[cell], 1);
  pts4[(b << 15) + pos] = make_float4(t, p, __int_as_float(n), 0.0f);
  if (j < N_PTS) {
    int p1 = atomicAdd(&cursor1[bits1[j] >> 16], 1);
    sorted1[p1] = j;
    int p2 = atomicAdd(&cursor2[bits2[j] >> 16], 1);
    sorted2[p2] = j;
  }
}

__device__ __forceinline__ int exact_rank(const uint32_t* __restrict__ bits,
                                          const int* __restrict__ prefix,
                                          const int* __restrict__ hist,
                                          const int* __restrict__ sorted, int j) {
  uint32_t my = bits[j];
  int b = (int)(my >> 16);
  int start = prefix[b];
  int cnt = hist[b];
  int r = start;
  for (int i = 0; i < cnt; ++i) {
    int m = sorted[start + i];
    uint32_t vb = bits[m];
    if (vb < my || (vb == my && m < j)) ++r;
  }
  return r;
}

__global__ __launch_bounds__(256) void rank_scatter1_kernel(
    const uint32_t* __restrict__ bits1, const uint32_t* __restrict__ bits2,
    const int* __restrict__ prefix1, const int* __restrict__ prefix2,
    const int* __restrict__ hist1, const int* __restrict__ hist2,
    const int* __restrict__ sorted1, const int* __restrict__ sorted2,
    int* __restrict__ xmid, int* __restrict__ rank2) {
  int j = blockIdx.x * 256 + threadIdx.x;
  int r1 = exact_rank(bits1, prefix1, hist1, sorted1, j);
  xmid[r1] = j;
  rank2[j] = exact_rank(bits2, prefix2, hist2, sorted2, j);
}

__global__ __launch_bounds__(256) void scatter2_kernel(const int* __restrict__ rank2,
                                                       const int* __restrict__ xmid,
                                                       int* __restrict__ xfin) {
  int p = blockIdx.x * 256 + threadIdx.x;
  xfin[rank2[p]] = xmid[p];
}

// -------- neighbor selection: one WAVE per center (4 waves/block) --------
__global__ __launch_bounds__(256) void select_kernel(
    const float* __restrict__ theta, const float* __restrict__ phi,
    const int* __restrict__ cent,
    const int* __restrict__ cellpre, const int* __restrict__ cellcnt,
    const float4* __restrict__ pts4,
    int* __restrict__ idx_buf, float* __restrict__ out_ct, float* __restrict__ out_cp) {
  __shared__ float wsc[4][CAPW];
  __shared__ int wsn[4][CAPW];
  int tid = threadIdx.x;
  int w = tid >> 6, lane = tid & 63;
  int bm = blockIdx.x * 4 + w;
  int b = bm >> 10, m = bm & 1023;
  int ci = cent[m];
  float ctv = theta[(b << 15) + ci];
  float cpv = phi[(b << 15) + ci];
  if (lane == 0) { out_ct[bm] = ctv; out_cp[bm] = cpv; }

  Key2 root; root.a = 0u; root.b = 42u;
  Key2 k2 = tf_block(root, 0u, 1u);              // split(key)[1] -> scores key
  uint32_t flat_base = (uint32_t)bm << 15;

  int tc = cell_t(ctv), pc = cell_p(cpv);
  int t0 = max(0, tc - 1), t1 = min(GT - 1, tc + 1);
  int p0 = max(0, pc - 1), p1 = min(GP - 1, pc + 1);
  int nct = t1 - t0 + 1, ncp = p1 - p0 + 1, ncells = nct * ncp;

  // lane < ncells loads its cell descriptor; broadcast all to the wave
  int cst = 0, ccn = 0;
  if (lane < ncells) {
    int cell = b * NCELL + (t0 + lane / ncp) * GP + (p0 + lane % ncp);
    cst = cellpre[cell];
    ccn = cellcnt[cell];
  }
  int sc9[9], cc9[9];
#pragma unroll
  for (int k = 0; k < 9; ++k) {
    sc9[k] = __shfl(cst, k);
    cc9[k] = __shfl(ccn, k);
  }
  int T = 0;
#pragma unroll
  for (int k = 0; k < 9; ++k) T += cc9[k];

  const float4* bpts = pts4 + ((size_t)b << 15);
  int wcnt = 0;
  for (int base = 0; base < T; base += 64) {
    int i = base + lane;
    bool hit = false; float sc = 0.0f; int n = 0;
    if (i < T) {
      int gidx = 0, acc = 0;
#pragma unroll
      for (int k = 0; k < 9; ++k) {
        int lo = acc; acc += cc9[k];
        if (i >= lo && i < acc) gidx = sc9[k] + (i - lo);
      }
      float4 pt = bpts[gidx];
      // match XLA's uncontracted f32 elementwise chain exactly
      float dx = __fsub_rn(pt.x, ctv);
      float dy = __fsub_rn(pt.y, cpv);
      float d = __fsqrt_rn(__fadd_rn(__fmul_rn(dx, dx), __fmul_rn(dy, dy)));
      if (d <= 0.1f) {
        hit = true; n = __float_as_int(pt.z);
        Key2 r = tf_block(k2, 0u, flat_base + (uint32_t)n);
        uint32_t bits = r.a ^ r.b;
        sc = __uint_as_float(0x3f800000u | (bits >> 9)) - 1.0f; // uniform [0,1)
      }
    }
    unsigned long long mask = __ballot(hit);
    int pos = wcnt + __popcll(mask & ((1ull << lane) - 1ull));
    if (hit && pos < CAPW) { wsc[w][pos] = sc; wsn[w][pos] = n; }
    wcnt = min(wcnt + (int)__popcll(mask), CAPW);
  }

  int mysel;
  if (wcnt <= 64) {
    // FAST PATH: 64-lane bitonic sort by lex (score, n) ascending.
    // Total order (n unique) => identical picks to stable top_k.
    float s = (lane < wcnt) ? wsc[w][lane] : 3.0e38f;
    int n = (lane < wcnt) ? wsn[w][lane] : 0x7fffffff;
#pragma unroll
    for (int k = 2; k <= 64; k <<= 1) {
#pragma unroll
      for (int jj = k >> 1; jj > 0; jj >>= 1) {
        float os = __shfl_xor(s, jj);
        int on = __shfl_xor(n, jj);
        bool lower = (lane & jj) == 0;
        bool dir = (lane & k) == 0;
        bool mineFirst = (s < os) || (s == os && n < on);
        bool takeMine = ((lower == mineFirst) == dir);
        s = takeMine ? s : os;
        n = takeMine ? n : on;
      }
    }
    int n0 = __shfl(n, 0);                        // argmin -> pad value
    mysel = (lane < wcnt) ? n : n0;
  } else {
    // SLOW PATH (wcnt>64, ~5%): 32 rounds of lex-min strictly after last pick
    float ls = -1.0f; int ln = -1;
    int sel0 = -1; mysel = -1;
    for (int r = 0; r < NS; ++r) {
      float best = 3.0e38f; int bn = 0x7fffffff;
      for (int i = lane; i < wcnt; i += 64) {
        float s = wsc[w][i]; int n = wsn[w][i];
        bool after = (s > ls) || (s == ls && n > ln);
        bool better = (s < best) || (s == best && n < bn);
        if (after && better) { best = s; bn = n; }
      }
      for (int off = 32; off; off >>= 1) {
        float os = __shfl_xor(best, off);
        int on = __shfl_xor(bn, off);
        if (os < best || (os == best && on < bn)) { best = os; bn = on; }
      }
      int chosen;
      if (best < 3.0e38f) { ls = best; ln = bn; chosen = bn; }
      else chosen = sel0;
      if (r == 0) sel0 = chosen;
      if (lane == r) mysel = chosen;
    }
  }
  if (lane < NS) idx_buf[bm * NS + lane] = mysel;
}

// -------- MLP: barrier-free per-position streaming kernels --------
__device__ __forceinline__ float bn_relu(float y, float mu, float r, float g, float be) {
  float t = __fsub_rn(y, mu);
  t = __fmul_rn(t, r);
  t = __fmul_rn(t, g);
  t = __fadd_rn(t, be);
  return fmaxf(t, 0.0f);
}

// L1: one thread per (bm, s). Gather 16 feats, 512 FMA, write Y1, stats1.
__global__ __launch_bounds__(256) void l1_kernel(
    const float* __restrict__ feat, const float* __restrict__ featT,
    const int* __restrict__ idx_buf,
    const float* __restrict__ w0, const float* __restrict__ b0,
    float* __restrict__ Y1g, double* __restrict__ stats, int useT) {
  int j = blockIdx.x * 256 + threadIdx.x;        // position id
  int bm = j >> 5, s = j & 31, b = bm >> 10;
  int lane = threadIdx.x & 63;
  int idx = idx_buf[j];                          // coalesced
  float x[16];
  if (useT) {
    const float4* src = reinterpret_cast<const float4*>(
        featT + (((size_t)b << 15) + (size_t)idx) * 16);
#pragma unroll
    for (int q = 0; q < 4; ++q) {
      float4 f = src[q];
      x[q * 4 + 0] = f.x; x[q * 4 + 1] = f.y;
      x[q * 4 + 2] = f.z; x[q * 4 + 3] = f.w;
    }
  } else {
#pragma unroll
    for (int c = 0; c < 16; ++c)
      x[c] = feat[((size_t)(b * 16 + c) << 15) + idx];
  }
  float y[32];
#pragma unroll
  for (int o = 0; o < 32; ++o) {
    float acc = b0[o];
#pragma unroll
    for (int c = 0; c < 16; ++c) acc = fmaf(w0[o * 16 + c], x[c], acc);
    y[o] = acc;
    Y1g[(size_t)bm * 1024 + o * 32 + s] = acc;
  }
  int rep = (j >> 6) & (NR - 1);
  double* base = stats + (size_t)rep * 64;
#pragma unroll
  for (int o = 0; o < 32; ++o) {
    float s1 = y[o], s2 = y[o] * y[o];
#pragma unroll
    for (int off = 32; off; off >>= 1) {
      s1 += __shfl_xor(s1, off);
      s2 += __shfl_xor(s2, off);
    }
    if (lane == 0) {
      atomicAdd(base + o, (double)s1);
      atomicAdd(base + 32 + o, (double)s2);
    }
  }
}

// L2: stats only (Y2 recomputed cheaply in l3). 1024 FMA/thread, no writes.
__global__ __launch_bounds__(256) void l2_kernel(
    const float* __restrict__ Y1g,
    const float* __restrict__ mur1, const float* __restrict__ g0, const float* __restrict__ be0,
    const float* __restrict__ w1, const float* __restrict__ b1,
    double* __restrict__ stats) {
  int j = blockIdx.x * 256 + threadIdx.x;
  int bm = j >> 5, s = j & 31;
  int lane = threadIdx.x & 63;
  float x2[32];
#pragma unroll
  for (int c = 0; c < 32; ++c)
    x2[c] = bn_relu(Y1g[(size_t)bm * 1024 + c * 32 + s],
                    mur1[c], mur1[32 + c], g0[c], be0[c]);
  int rep = (j >> 6) & (NR - 1);
  double* base = stats + (size_t)rep * 64;
#pragma unroll
  for (int o = 0; o < 32; ++o) {
    float acc = b1[o];
#pragma unroll
    for (int c = 0; c < 32; ++c) acc = fmaf(w1[o * 32 + c], x2[c], acc);
    float s1 = acc, s2 = acc * acc;
#pragma unroll
    for (int off = 32; off; off >>= 1) {
      s1 += __shfl_xor(s1, off);
      s2 += __shfl_xor(s2, off);
    }
    if (lane == 0) {
      atomicAdd(base + o, (double)s1);
      atomicAdd(base + 32 + o, (double)s2);
    }
  }
}

// L3: recompute L2 (bit-identical), bn2+relu, L3; stats3 + per-(bm,o) min/max.
__global__ __launch_bounds__(256) void l3_kernel(
    const float* __restrict__ Y1g,
    const float* __restrict__ mur1, const float* __restrict__ g0, const float* __restrict__ be0,
    const float* __restrict__ w1, const float* __restrict__ b1,
    const float* __restrict__ mur2, const float* __restrict__ g1, const float* __restrict__ be1,
    const float* __restrict__ w2, const float* __restrict__ b2,
    float* __restrict__ mm3, double* __restrict__ stats) {
  int j = blockIdx.x * 256 + threadIdx.x;
  int bm = j >> 5, s = j & 31;
  int lane = threadIdx.x & 63;
  float x2[32];
#pragma unroll
  for (int c = 0; c < 32; ++c)
    x2[c] = bn_relu(Y1g[(size_t)bm * 1024 + c * 32 + s],
                    mur1[c], mur1[32 + c], g0[c], be0[c]);
  float x3[32];
#pragma unroll
  for (int o = 0; o < 32; ++o) {
    float acc = b1[o];
#pragma unroll
    for (int c = 0; c < 32; ++c) acc = fmaf(w1[o * 32 + c], x2[c], acc);
    x3[o] = bn_relu(acc, mur2[o], mur2[32 + o], g1[o], be1[o]);
  }
  int rep = (j >> 6) & (NR - 1);
  double* base = stats + (size_t)rep * 128;
#pragma unroll
  for (int o = 0; o < 64; ++o) {
    float acc = b2[o];
#pragma unroll
    for (int c = 0; c < 32; ++c) acc = fmaf(w2[o * 32 + c], x3[c], acc);
    // stats: full-wave reduce (covers 2 bm positions -> valid global partial)
    float s1 = acc, s2 = acc * acc;
#pragma unroll
    for (int off = 32; off; off >>= 1) {
      s1 += __shfl_xor(s1, off);
      s2 += __shfl_xor(s2, off);
    }
    if (lane == 0) {
      atomicAdd(base + o, (double)s1);
      atomicAdd(base + 64 + o, (double)s2);
    }
    // min/max: half-wave reduce (32 lanes == the 32 s of this bm)
    float mx = acc, mn = acc;
#pragma unroll
    for (int off = 16; off; off >>= 1) {
      mx = fmaxf(mx, __shfl_xor(mx, off));
      mn = fminf(mn, __shfl_xor(mn, off));
    }
    if (s == 0) {
      mm3[bm * 128 + o * 2] = mx;
      mm3[bm * 128 + o * 2 + 1] = mn;
    }
  }
}

// final: BN3 on the extremum; exact because bn_relu is weakly monotone in y
__global__ __launch_bounds__(256) void final_small_kernel(
    const float* __restrict__ mm3,
    const float* __restrict__ mur3, const float* __restrict__ g2, const float* __restrict__ be2,
    float* __restrict__ out_ft) {
  int j = blockIdx.x * 256 + threadIdx.x;          // (b*64+o)*1024+m
  int b = j >> 16, o = (j >> 10) & 63, m = j & 1023;
  int bm = b * 1024 + m;
  float g = g2[o];
  float y = (g >= 0.0f) ? mm3[bm * 128 + o * 2] : mm3[bm * 128 + o * 2 + 1];
  out_ft[j] = bn_relu(y, mur3[o], mur3[64 + o], g, be2[o]);
}

template <int CO>
__global__ void fixup_mur_kernel(const double* __restrict__ S, float* __restrict__ mur) {
  int o = threadIdx.x;
  if (o >= CO) return;
  double s1 = 0.0, s2 = 0.0;
  for (int r = 0; r < NR; ++r) {
    s1 += S[r * 2 * CO + o];
    s2 += S[r * 2 * CO + CO + o];
  }
  const double P = (double)P_TOT;
  double mu = s1 / P;
  double var = s2 / P - mu * mu;
  mur[o] = (float)mu;
  mur[CO + o] = (float)(1.0 / sqrt(var + 1e-5));
}

extern "C" void kernel_launch(void* const* d_in, const int* in_sizes, int n_in,
                              void* d_out, int out_size, void* d_ws, size_t ws_size,
                              hipStream_t stream) {
  (void)in_sizes; (void)n_in; (void)out_size;
  const float* theta = (const float*)d_in[0];
  const float* phi   = (const float*)d_in[1];
  const float* feat  = (const float*)d_in[2];
  const float* w0 = (const float*)d_in[3];
  const float* b0 = (const float*)d_in[4];
  const float* g0 = (const float*)d_in[5];
  const float* be0 = (const float*)d_in[6];
  const float* w1 = (const float*)d_in[7];
  const float* b1 = (const float*)d_in[8];
  const float* g1 = (const float*)d_in[9];
  const float* be1 = (const float*)d_in[10];
  const float* w2 = (const float*)d_in[11];
  const float* b2 = (const float*)d_in[12];
  const float* g2 = (const float*)d_in[13];
  const float* be2 = (const float*)d_in[14];

  float* out = (float*)d_out;
  float* out_ct = out;
  float* out_cp = out + B_SZ * M_CENT;
  float* out_ft = out + 2 * B_SZ * M_CENT;

  char* ws = (char*)d_ws;
  uint32_t* bits1 = (uint32_t*)(ws + 0);          // 128K
  uint32_t* bits2 = (uint32_t*)(ws + 131072);     // 128K
  int* rank2 = (int*)(ws + 262144);               // 128K
  int* xmid  = (int*)(ws + 393216);               // 128K
  int* xfin  = (int*)(ws + 524288);               // 128K; [0:1024] == cent_idx
  int* idx_buf = (int*)(ws + 655360);             // 512K
  // ---- single contiguous memset region [1179648, 1867776) ----
  int* hist1   = (int*)(ws + 1179648);            // 256K
  int* hist2   = (int*)(ws + 1441792);            // 256K
  int* cellcnt = (int*)(ws + 1703936);            // 32K
  double* stats1 = (double*)(ws + 1736704);       // 32K
  double* stats2 = (double*)(ws + 1769472);       // 32K
  double* stats3 = (double*)(ws + 1802240);       // 64K -> end 1867776
  // ----
  int* prefix1 = (int*)(ws + 1867776);            // 256K
  int* prefix2 = (int*)(ws + 2129920);            // 256K
  int* cursor1 = (int*)(ws + 2392064);            // 256K
  int* cursor2 = (int*)(ws + 2654208);            // 256K
  int* sorted1 = (int*)(ws + 2916352);            // 128K
  int* sorted2 = (int*)(ws + 3047424);            // 128K
  int* gbase1  = (int*)(ws + 3178496);            // 1K
  int* gbase2  = (int*)(ws + 3179520);            // 1K
  int* cellpre = (int*)(ws + 3180544);            // 32K
  int* cellcur = (int*)(ws + 3213312);            // 32K
  float4* pts4 = (float4*)(ws + 3246080);         // 2M
  float* mur1 = (float*)(ws + 5343232);
  float* mur2 = (float*)(ws + 5343488);
  float* mur3 = (float*)(ws + 5343744);
  float* mm3  = (float*)(ws + 5344768);           // 2M
  float* Y1g  = (float*)(ws + 7441920);           // 16M (proven available: pass3s ran)
  float* featT = (float*)(ws + 7441920 + 16777216); // 8M (optional)
  size_t NEED_T = (size_t)7441920 + 16777216 + 8388608;
  int useT = (ws_size >= NEED_T) ? 1 : 0;

  hipMemsetAsync(ws + 1179648, 0, 688128, stream);  // hist1,hist2,cellcnt,stats1-3

  prep_kernel<<<512, 256, 0, stream>>>(theta, phi, bits1, bits2, hist1, hist2, cellcnt);
  if (useT)
    transpose_kernel<<<dim3(512, 4), 256, 0, stream>>>(feat, featT);
  scans_kernel<<<6, 256, 0, stream>>>(hist1, hist2, gbase1, gbase2,
                                      cellcnt, cellpre, cellcur);
  bucket_scan_kernel<<<dim3(256, 2), 256, 0, stream>>>(hist1, hist2, gbase1, gbase2,
                                                       prefix1, prefix2, cursor1, cursor2);
  scatter_kernel<<<512, 256, 0, stream>>>(theta, phi, cellcur, pts4,
                                          bits1, bits2, cursor1, cursor2,
                                          sorted1, sorted2);
  rank_scatter1_kernel<<<128, 256, 0, stream>>>(bits1, bits2, prefix1, prefix2,
                                                hist1, hist2, sorted1, sorted2,
                                                xmid, rank2);
  scatter2_kernel<<<128, 256, 0, stream>>>(rank2, xmid, xfin);

  select_kernel<<<1024, 256, 0, stream>>>(theta, phi, xfin, cellpre, cellcnt,
                                          pts4, idx_buf, out_ct, out_cp);

  l1_kernel<<<512, 256, 0, stream>>>(feat, featT, idx_buf, w0, b0, Y1g, stats1, useT);
  fixup_mur_kernel<32><<<1, 64, 0, stream>>>(stats1, mur1);
  l2_kernel<<<512, 256, 0, stream>>>(Y1g, mur1, g0, be0, w1, b1, stats2);
  fixup_mur_kernel<32><<<1, 64, 0, stream>>>(stats2, mur2);
  l3_kernel<<<512, 256, 0, stream>>>(Y1g, mur1, g0, be0, w1, b1,
                                     mur2, g1, be1, w2, b2, mm3, stats3);
  fixup_mur_kernel<64><<<1, 64, 0, stream>>>(stats3, mur3);
  final_small_kernel<<<1024, 256, 0, stream>>>(mm3, mur3, g2, be2, out_ft);
}

// Round 12
// 276.889 us; speedup vs baseline: 1.0415x; 1.0415x over previous
//
#include <hip/hip_runtime.h>
#include <stdint.h>

#define N_PTS 32768
#define M_CENT 1024
#define B_SZ 4
#define NS 32
#define NR 64
#define P_TOT (B_SZ * NS * M_CENT) /* 131072 */

#define GT 29
#define GP 58
#define NCELL (GT * GP) /* 1682 */
#define INVF (1.0f / 0.11f)
#define CAPW 320

__device__ __forceinline__ int cell_t(float t) {
  return min(GT - 1, (int)(t * INVF));
}
__device__ __forceinline__ int cell_p(float p) {
  return min(GP - 1, (int)(p * INVF));
}

// ---------------- threefry2x32 (JAX partitionable mode) ----------------
struct Key2 { uint32_t a, b; };

__device__ __forceinline__ uint32_t rotl32(uint32_t v, uint32_t r) {
  return (v << r) | (v >> (32u - r));
}

__device__ __forceinline__ void tf2x32(uint32_t k0, uint32_t k1,
                                       uint32_t& x0, uint32_t& x1) {
  uint32_t ks0 = k0, ks1 = k1, ks2 = k0 ^ k1 ^ 0x1BD11BDAu;
  x0 += ks0; x1 += ks1;
#define TF_ROUND(r) { x0 += x1; x1 = rotl32(x1, r); x1 ^= x0; }
  TF_ROUND(13u) TF_ROUND(15u) TF_ROUND(26u) TF_ROUND(6u)
  x0 += ks1; x1 += ks2 + 1u;
  TF_ROUND(17u) TF_ROUND(29u) TF_ROUND(16u) TF_ROUND(24u)
  x0 += ks2; x1 += ks0 + 2u;
  TF_ROUND(13u) TF_ROUND(15u) TF_ROUND(26u) TF_ROUND(6u)
  x0 += ks0; x1 += ks1 + 3u;
  TF_ROUND(17u) TF_ROUND(29u) TF_ROUND(16u) TF_ROUND(24u)
  x0 += ks1; x1 += ks2 + 4u;
  TF_ROUND(13u) TF_ROUND(15u) TF_ROUND(26u) TF_ROUND(6u)
  x0 += ks2; x1 += ks0 + 5u;
#undef TF_ROUND
}

__device__ __forceinline__ Key2 tf_block(Key2 k, uint32_t hi, uint32_t lo) {
  uint32_t x0 = hi, x1 = lo;
  tf2x32(k.a, k.b, x0, x1);
  Key2 r; r.a = x0; r.b = x1; return r;
}

// -------- prep: perm bits + bucket hist (j<32768) and cell hist (all j) --------
__global__ __launch_bounds__(256) void prep_kernel(const float* __restrict__ theta,
                                                   const float* __restrict__ phi,
                                                   uint32_t* __restrict__ bits1,
                                                   uint32_t* __restrict__ bits2,
                                                   int* __restrict__ hist1,
                                                   int* __restrict__ hist2,
                                                   int* __restrict__ cellcnt) {
  int j = blockIdx.x * 256 + threadIdx.x;        // 0 .. 131071
  int b = j >> 15;
  float t = theta[j], p = phi[j];
  atomicAdd(&cellcnt[b * NCELL + cell_t(t) * GP + cell_p(p)], 1);
  if (j < N_PTS) {
    Key2 root; root.a = 0u; root.b = 42u;        // jax.random.key(42)
    Key2 k1   = tf_block(root, 0u, 0u);          // split(key)[0] -> permutation key
    Key2 keyA = tf_block(k1, 0u, 0u);
    Key2 sub1 = tf_block(k1, 0u, 1u);
    Key2 sub2 = tf_block(keyA, 0u, 1u);
    Key2 r1 = tf_block(sub1, 0u, (uint32_t)j);
    Key2 r2 = tf_block(sub2, 0u, (uint32_t)j);
    uint32_t v1 = r1.a ^ r1.b, v2 = r2.a ^ r2.b;
    bits1[j] = v1; bits2[j] = v2;
    atomicAdd(&hist1[v1 >> 16], 1);
    atomicAdd(&hist2[v2 >> 16], 1);
  }
}

// -------- feat transpose: [B][16][N] -> [B][N][16] --------
__global__ __launch_bounds__(256) void transpose_kernel(const float* __restrict__ feat,
                                                        float* __restrict__ featT) {
  __shared__ float lds[16][65];
  int b = blockIdx.y;
  int n0 = blockIdx.x * 64;
  int tid = threadIdx.x;
#pragma unroll
  for (int k = 0; k < 4; ++k) {
    int v = tid + k * 256;
    int c = v >> 6, no = v & 63;
    lds[c][no] = feat[((size_t)(b * 16 + c) << 15) + n0 + no];
  }
  __syncthreads();
#pragma unroll
  for (int k = 0; k < 4; ++k) {
    int v = tid + k * 256;
    int no = v >> 4, c = v & 15;
    featT[((size_t)(b << 15) + n0 + no) * 16 + c] = lds[c][no];
  }
}

// -------- fused scans --------
__global__ __launch_bounds__(256) void scans_kernel(const int* __restrict__ hist1,
                                                    const int* __restrict__ hist2,
                                                    int* __restrict__ gbase1,
                                                    int* __restrict__ gbase2,
                                                    const int* __restrict__ cellcnt,
                                                    int* __restrict__ cellpre,
                                                    int* __restrict__ cellcur) {
  __shared__ int s[256];
  int t = threadIdx.x;
  if (blockIdx.x < 2) {
    const int* hist = blockIdx.x == 0 ? hist1 : hist2;
    int* gbase = blockIdx.x == 0 ? gbase1 : gbase2;
    int sum = 0;
    for (int i = 0; i < 256; ++i) sum += hist[t * 256 + i];
    s[t] = sum;
    __syncthreads();
    if (t == 0) {
      int run = 0;
      for (int i = 0; i < 256; ++i) { int v = s[i]; s[i] = run; run += v; }
    }
    __syncthreads();
    gbase[t] = s[t];
  } else {
    int b = blockIdx.x - 2;
    const int* cnt = cellcnt + b * NCELL;
    int i0 = t * 7, i1 = min(i0 + 7, NCELL);
    int sum = 0;
    for (int i = i0; i < i1; ++i) sum += cnt[i];
    s[t] = sum;
    __syncthreads();
    for (int off = 1; off < 256; off <<= 1) {
      int v = (t >= off) ? s[t - off] : 0;
      __syncthreads();
      s[t] += v;
      __syncthreads();
    }
    int run = (t == 0) ? 0 : s[t - 1];
    for (int i = i0; i < i1; ++i) {
      cellpre[b * NCELL + i] = run;
      cellcur[b * NCELL + i] = run;
      run += cnt[i];
    }
  }
}

__global__ __launch_bounds__(256) void bucket_scan_kernel(const int* __restrict__ hist1,
                                                          const int* __restrict__ hist2,
                                                          const int* __restrict__ gbase1,
                                                          const int* __restrict__ gbase2,
                                                          int* __restrict__ prefix1,
                                                          int* __restrict__ prefix2,
                                                          int* __restrict__ cursor1,
                                                          int* __restrict__ cursor2) {
  __shared__ int s[256];
  const int* hist = blockIdx.y == 0 ? hist1 : hist2;
  const int* gbase = blockIdx.y == 0 ? gbase1 : gbase2;
  int* prefix = blockIdx.y == 0 ? prefix1 : prefix2;
  int* cursor = blockIdx.y == 0 ? cursor1 : cursor2;
  int g = blockIdx.x, t = threadIdx.x;
  int idx = g * 256 + t;
  int orig = hist[idx];
  s[t] = orig;
  __syncthreads();
  for (int off = 1; off < 256; off <<= 1) {
    int v = (t >= off) ? s[t - off] : 0;
    __syncthreads();
    s[t] += v;
    __syncthreads();
  }
  int pref = gbase[g] + s[t] - orig;
  prefix[idx] = pref;
  cursor[idx] = pref;
}

// -------- fused scatters --------
__global__ __launch_bounds__(256) void scatter_kernel(const float* __restrict__ theta,
                                                      const float* __restrict__ phi,
                                                      int* __restrict__ cellcur,
                                                      float4* __restrict__ pts4,
                                                      const uint32_t* __restrict__ bits1,
                                                      const uint32_t* __restrict__ bits2,
                                                      int* __restrict__ cursor1,
                                                      int* __restrict__ cursor2,
                                                      int* __restrict__ sorted1,
                                                      int* __restrict__ sorted2) {
  int j = blockIdx.x * 256 + threadIdx.x;
  int b = j >> 15, n = j & (N_PTS - 1);
  float t = theta[j], p = phi[j];
  int cell = b * NCELL + cell_t(t) * GP + cell_p(p);
  int pos = atomicAdd(&cellcur[cell], 1);
  pts4[(b << 15) + pos] = make_float4(t, p, __int_as_float(n), 0.0f);
  if (j < N_PTS) {
    int p1 = atomicAdd(&cursor1[bits1[j] >> 16], 1);
    sorted1[p1] = j;
    int p2 = atomicAdd(&cursor2[bits2[j] >> 16], 1);
    sorted2[p2] = j;
  }
}

__device__ __forceinline__ int exact_rank(const uint32_t* __restrict__ bits,
                                          const int* __restrict__ prefix,
                                          const int* __restrict__ hist,
                                          const int* __restrict__ sorted, int j) {
  uint32_t my = bits[j];
  int b = (int)(my >> 16);
  int start = prefix[b];
  int cnt = hist[b];
  int r = start;
  for (int i = 0; i < cnt; ++i) {
    int m = sorted[start + i];
    uint32_t vb = bits[m];
    if (vb < my || (vb == my && m < j)) ++r;
  }
  return r;
}

__global__ __launch_bounds__(256) void rank_scatter1_kernel(
    const uint32_t* __restrict__ bits1, const uint32_t* __restrict__ bits2,
    const int* __restrict__ prefix1, const int* __restrict__ prefix2,
    const int* __restrict__ hist1, const int* __restrict__ hist2,
    const int* __restrict__ sorted1, const int* __restrict__ sorted2,
    int* __restrict__ xmid, int* __restrict__ rank2) {
  int j = blockIdx.x * 256 + threadIdx.x;
  int r1 = exact_rank(bits1, prefix1, hist1, sorted1, j);
  xmid[r1] = j;
  rank2[j] = exact_rank(bits2, prefix2, hist2, sorted2, j);
}

__global__ __launch_bounds__(256) void scatter2_kernel(const int* __restrict__ rank2,
                                                       const int* __restrict__ xmid,
                                                       int* __restrict__ xfin) {
  int p = blockIdx.x * 256 + threadIdx.x;
  xfin[rank2[p]] = xmid[p];
}

// -------- neighbor selection: one WAVE per center (4 waves/block) --------
__global__ __launch_bounds__(256) void select_kernel(
    const float* __restrict__ theta, const float* __restrict__ phi,
    const int* __restrict__ cent,
    const int* __restrict__ cellpre, const int* __restrict__ cellcnt,
    const float4* __restrict__ pts4,
    int* __restrict__ idx_buf, float* __restrict__ out_ct, float* __restrict__ out_cp) {
  __shared__ float wsc[4][CAPW];
  __shared__ int wsn[4][CAPW];
  int tid = threadIdx.x;
  int w = tid >> 6, lane = tid & 63;
  int bm = blockIdx.x * 4 + w;
  int b = bm >> 10, m = bm & 1023;
  int ci = cent[m];
  float ctv = theta[(b << 15) + ci];
  float cpv = phi[(b << 15) + ci];
  if (lane == 0) { out_ct[bm] = ctv; out_cp[bm] = cpv; }

  Key2 root; root.a = 0u; root.b = 42u;
  Key2 k2 = tf_block(root, 0u, 1u);              // split(key)[1] -> scores key
  uint32_t flat_base = (uint32_t)bm << 15;

  int tc = cell_t(ctv), pc = cell_p(cpv);
  int t0 = max(0, tc - 1), t1 = min(GT - 1, tc + 1);
  int p0 = max(0, pc - 1), p1 = min(GP - 1, pc + 1);
  int nct = t1 - t0 + 1, ncp = p1 - p0 + 1, ncells = nct * ncp;

  int cst = 0, ccn = 0;
  if (lane < ncells) {
    int cell = b * NCELL + (t0 + lane / ncp) * GP + (p0 + lane % ncp);
    cst = cellpre[cell];
    ccn = cellcnt[cell];
  }
  int sc9[9], cc9[9];
#pragma unroll
  for (int k = 0; k < 9; ++k) {
    sc9[k] = __shfl(cst, k);
    cc9[k] = __shfl(ccn, k);
  }
  int T = 0;
#pragma unroll
  for (int k = 0; k < 9; ++k) T += cc9[k];

  const float4* bpts = pts4 + ((size_t)b << 15);
  int wcnt = 0;
  for (int base = 0; base < T; base += 64) {
    int i = base + lane;
    bool hit = false; float sc = 0.0f; int n = 0;
    if (i < T) {
      int gidx = 0, acc = 0;
#pragma unroll
      for (int k = 0; k < 9; ++k) {
        int lo = acc; acc += cc9[k];
        if (i >= lo && i < acc) gidx = sc9[k] + (i - lo);
      }
      float4 pt = bpts[gidx];
      float dx = __fsub_rn(pt.x, ctv);
      float dy = __fsub_rn(pt.y, cpv);
      float d = __fsqrt_rn(__fadd_rn(__fmul_rn(dx, dx), __fmul_rn(dy, dy)));
      if (d <= 0.1f) {
        hit = true; n = __float_as_int(pt.z);
        Key2 r = tf_block(k2, 0u, flat_base + (uint32_t)n);
        uint32_t bits = r.a ^ r.b;
        sc = __uint_as_float(0x3f800000u | (bits >> 9)) - 1.0f; // uniform [0,1)
      }
    }
    unsigned long long mask = __ballot(hit);
    int pos = wcnt + __popcll(mask & ((1ull << lane) - 1ull));
    if (hit && pos < CAPW) { wsc[w][pos] = sc; wsn[w][pos] = n; }
    wcnt = min(wcnt + (int)__popcll(mask), CAPW);
  }

  int mysel;
  if (wcnt <= 64) {
    float s = (lane < wcnt) ? wsc[w][lane] : 3.0e38f;
    int n = (lane < wcnt) ? wsn[w][lane] : 0x7fffffff;
#pragma unroll
    for (int k = 2; k <= 64; k <<= 1) {
#pragma unroll
      for (int jj = k >> 1; jj > 0; jj >>= 1) {
        float os = __shfl_xor(s, jj);
        int on = __shfl_xor(n, jj);
        bool lower = (lane & jj) == 0;
        bool dir = (lane & k) == 0;
        bool mineFirst = (s < os) || (s == os && n < on);
        bool takeMine = ((lower == mineFirst) == dir);
        s = takeMine ? s : os;
        n = takeMine ? n : on;
      }
    }
    int n0 = __shfl(n, 0);
    mysel = (lane < wcnt) ? n : n0;
  } else {
    float ls = -1.0f; int ln = -1;
    int sel0 = -1; mysel = -1;
    for (int r = 0; r < NS; ++r) {
      float best = 3.0e38f; int bn = 0x7fffffff;
      for (int i = lane; i < wcnt; i += 64) {
        float s = wsc[w][i]; int n = wsn[w][i];
        bool after = (s > ls) || (s == ls && n > ln);
        bool better = (s < best) || (s == best && n < bn);
        if (after && better) { best = s; bn = n; }
      }
      for (int off = 32; off; off >>= 1) {
        float os = __shfl_xor(best, off);
        int on = __shfl_xor(bn, off);
        if (os < best || (os == best && on < bn)) { best = os; bn = on; }
      }
      int chosen;
      if (best < 3.0e38f) { ls = best; ln = bn; chosen = bn; }
      else chosen = sel0;
      if (r == 0) sel0 = chosen;
      if (lane == r) mysel = chosen;
    }
  }
  if (lane < NS) idx_buf[bm * NS + lane] = mysel;
}

// -------- MLP: register-FMA + LDS-staged reductions, 2 threads/position --------
__device__ __forceinline__ float bn_relu(float y, float mu, float r, float g, float be) {
  float t = __fsub_rn(y, mu);
  t = __fmul_rn(t, r);
  t = __fmul_rn(t, g);
  t = __fadd_rn(t, be);
  return fmaxf(t, 0.0f);
}

// L1: block = 128 positions x 2 halves. h computes 16 of 32 outputs.
__global__ __launch_bounds__(256) void l1_kernel(
    const float* __restrict__ feat, const float* __restrict__ featT,
    const int* __restrict__ idx_buf,
    const float* __restrict__ w0, const float* __restrict__ b0,
    float* __restrict__ Y1g, double* __restrict__ stats, int useT) {
  __shared__ float y1s[128 * 34];
  int tid = threadIdx.x;
  int pl = tid & 127, h = tid >> 7;
  int pg = blockIdx.x * 128 + pl;
  int bm = pg >> 5, s = pg & 31, b = bm >> 10;
  int idx = idx_buf[pg];
  float x[16];
  if (useT) {
    const float4* src = reinterpret_cast<const float4*>(
        featT + (((size_t)b << 15) + (size_t)idx) * 16);
#pragma unroll
    for (int q = 0; q < 4; ++q) {
      float4 f = src[q];
      x[q * 4 + 0] = f.x; x[q * 4 + 1] = f.y;
      x[q * 4 + 2] = f.z; x[q * 4 + 3] = f.w;
    }
  } else {
#pragma unroll
    for (int c = 0; c < 16; ++c)
      x[c] = feat[((size_t)(b * 16 + c) << 15) + idx];
  }
#pragma unroll
  for (int oo = 0; oo < 16; ++oo) {
    int o = h * 16 + oo;
    float acc = b0[o];
#pragma unroll
    for (int c = 0; c < 16; ++c) acc = fmaf(w0[o * 16 + c], x[c], acc);
    Y1g[(size_t)bm * 1024 + o * 32 + s] = acc;
    y1s[pl * 34 + o] = acc;
  }
  __syncthreads();
  // stats: thread (ch 0..31, seg 0..7) sums 16 positions
  int ch = tid & 31, seg = tid >> 5;
  float s1 = 0.0f, s2 = 0.0f;
#pragma unroll
  for (int i = 0; i < 16; ++i) {
    float v = y1s[(seg * 16 + i) * 34 + ch];
    s1 += v; s2 += v * v;
  }
  double* base = stats + (size_t)(blockIdx.x & (NR - 1)) * 64;
  atomicAdd(base + ch, (double)s1);
  atomicAdd(base + 32 + ch, (double)s2);
}

// L2: stats2 only. h computes 16 of 32 L2 outputs; x2 dup per half.
__global__ __launch_bounds__(256) void l2_kernel(
    const float* __restrict__ Y1g,
    const float* __restrict__ mur1, const float* __restrict__ g0, const float* __restrict__ be0,
    const float* __restrict__ w1, const float* __restrict__ b1,
    double* __restrict__ stats) {
  __shared__ float y2s[128 * 34];
  int tid = threadIdx.x;
  int pl = tid & 127, h = tid >> 7;
  int pg = blockIdx.x * 128 + pl;
  int bm = pg >> 5, s = pg & 31;
  float x2[32];
#pragma unroll
  for (int c = 0; c < 32; ++c)
    x2[c] = bn_relu(Y1g[(size_t)bm * 1024 + c * 32 + s],
                    mur1[c], mur1[32 + c], g0[c], be0[c]);
#pragma unroll
  for (int oo = 0; oo < 16; ++oo) {
    int o = h * 16 + oo;
    float acc = b1[o];
#pragma unroll
    for (int c = 0; c < 32; ++c) acc = fmaf(w1[o * 32 + c], x2[c], acc);
    y2s[pl * 34 + o] = acc;
  }
  __syncthreads();
  int ch = tid & 31, seg = tid >> 5;
  float s1 = 0.0f, s2 = 0.0f;
#pragma unroll
  for (int i = 0; i < 16; ++i) {
    float v = y2s[(seg * 16 + i) * 34 + ch];
    s1 += v; s2 += v * v;
  }
  double* base = stats + (size_t)(blockIdx.x & (NR - 1)) * 64;
  atomicAdd(base + ch, (double)s1);
  atomicAdd(base + 32 + ch, (double)s2);
}

// L3: h computes x3-half (shared via LDS), then 32 of 64 L3 outputs.
// smem reused: x3 view [128][34] -> y3 view [128][66].
__global__ __launch_bounds__(256) void l3_kernel(
    const float* __restrict__ Y1g,
    const float* __restrict__ mur1, const float* __restrict__ g0, const float* __restrict__ be0,
    const float* __restrict__ w1, const float* __restrict__ b1,
    const float* __restrict__ mur2, const float* __restrict__ g1, const float* __restrict__ be1,
    const float* __restrict__ w2, const float* __restrict__ b2,
    float* __restrict__ mm3, double* __restrict__ stats) {
  __shared__ float smem[128 * 66];
  int tid = threadIdx.x;
  int pl = tid & 127, h = tid >> 7;
  int pg = blockIdx.x * 128 + pl;
  int bm = pg >> 5, s = pg & 31;
  float x2[32];
#pragma unroll
  for (int c = 0; c < 32; ++c)
    x2[c] = bn_relu(Y1g[(size_t)bm * 1024 + c * 32 + s],
                    mur1[c], mur1[32 + c], g0[c], be0[c]);
  // x3 half -> LDS
#pragma unroll
  for (int cc = 0; cc < 16; ++cc) {
    int c = h * 16 + cc;
    float acc = b1[c];
#pragma unroll
    for (int k = 0; k < 32; ++k) acc = fmaf(w1[c * 32 + k], x2[k], acc);
    smem[pl * 34 + c] = bn_relu(acc, mur2[c], mur2[32 + c], g1[c], be1[c]);
  }
  __syncthreads();
  float x3[32];
#pragma unroll
  for (int c = 0; c < 32; ++c) x3[c] = smem[pl * 34 + c];
  __syncthreads();                                // before smem reuse
  // y3: 32 outputs (half h) -> LDS [128][66]
#pragma unroll
  for (int oo = 0; oo < 32; ++oo) {
    int o = h * 32 + oo;
    float acc = b2[o];
#pragma unroll
    for (int c = 0; c < 32; ++c) acc = fmaf(w2[o * 32 + c], x3[c], acc);
    smem[pl * 66 + o] = acc;
  }
  __syncthreads();
  // stats + minmax: thread (ch 0..63, bmq 0..3) over 32 positions
  int ch = tid & 63, bmq = tid >> 6;
  float s1 = 0.0f, s2 = 0.0f, mx = -3.0e38f, mn = 3.0e38f;
#pragma unroll
  for (int i = 0; i < 32; ++i) {
    float v = smem[(bmq * 32 + i) * 66 + ch];
    s1 += v; s2 += v * v;
    mx = fmaxf(mx, v); mn = fminf(mn, v);
  }
  double* base = stats + (size_t)(blockIdx.x & (NR - 1)) * 128;
  atomicAdd(base + ch, (double)s1);
  atomicAdd(base + 64 + ch, (double)s2);
  int bmg = blockIdx.x * 4 + bmq;
  mm3[bmg * 128 + ch * 2] = mx;
  mm3[bmg * 128 + ch * 2 + 1] = mn;
}

// final: BN3 on the extremum; exact because bn_relu is weakly monotone in y
__global__ __launch_bounds__(256) void final_small_kernel(
    const float* __restrict__ mm3,
    const float* __restrict__ mur3, const float* __restrict__ g2, const float* __restrict__ be2,
    float* __restrict__ out_ft) {
  int j = blockIdx.x * 256 + threadIdx.x;          // (b*64+o)*1024+m
  int b = j >> 16, o = (j >> 10) & 63, m = j & 1023;
  int bm = b * 1024 + m;
  float g = g2[o];
  float y = (g >= 0.0f) ? mm3[bm * 128 + o * 2] : mm3[bm * 128 + o * 2 + 1];
  out_ft[j] = bn_relu(y, mur3[o], mur3[64 + o], g, be2[o]);
}

template <int CO>
__global__ void fixup_mur_kernel(const double* __restrict__ S, float* __restrict__ mur) {
  int o = threadIdx.x;
  if (o >= CO) return;
  double s1 = 0.0, s2 = 0.0;
  for (int r = 0; r < NR; ++r) {
    s1 += S[r * 2 * CO + o];
    s2 += S[r * 2 * CO + CO + o];
  }
  const double P = (double)P_TOT;
  double mu = s1 / P;
  double var = s2 / P - mu * mu;
  mur[o] = (float)mu;
  mur[CO + o] = (float)(1.0 / sqrt(var + 1e-5));
}

extern "C" void kernel_launch(void* const* d_in, const int* in_sizes, int n_in,
                              void* d_out, int out_size, void* d_ws, size_t ws_size,
                              hipStream_t stream) {
  (void)in_sizes; (void)n_in; (void)out_size;
  const float* theta = (const float*)d_in[0];
  const float* phi   = (const float*)d_in[1];
  const float* feat  = (const float*)d_in[2];
  const float* w0 = (const float*)d_in[3];
  const float* b0 = (const float*)d_in[4];
  const float* g0 = (const float*)d_in[5];
  const float* be0 = (const float*)d_in[6];
  const float* w1 = (const float*)d_in[7];
  const float* b1 = (const float*)d_in[8];
  const float* g1 = (const float*)d_in[9];
  const float* be1 = (const float*)d_in[10];
  const float* w2 = (const float*)d_in[11];
  const float* b2 = (const float*)d_in[12];
  const float* g2 = (const float*)d_in[13];
  const float* be2 = (const float*)d_in[14];

  float* out = (float*)d_out;
  float* out_ct = out;
  float* out_cp = out + B_SZ * M_CENT;
  float* out_ft = out + 2 * B_SZ * M_CENT;

  char* ws = (char*)d_ws;
  uint32_t* bits1 = (uint32_t*)(ws + 0);
  uint32_t* bits2 = (uint32_t*)(ws + 131072);
  int* rank2 = (int*)(ws + 262144);
  int* xmid  = (int*)(ws + 393216);
  int* xfin  = (int*)(ws + 524288);      // xfin[0:1024] == cent_idx
  int* idx_buf = (int*)(ws + 655360);
  int* hist1   = (int*)(ws + 1179648);
  int* hist2   = (int*)(ws + 1441792);
  int* cellcnt = (int*)(ws + 1703936);
  double* stats1 = (double*)(ws + 1736704);
  double* stats2 = (double*)(ws + 1769472);
  double* stats3 = (double*)(ws + 1802240);
  int* prefix1 = (int*)(ws + 1867776);
  int* prefix2 = (int*)(ws + 2129920);
  int* cursor1 = (int*)(ws + 2392064);
  int* cursor2 = (int*)(ws + 2654208);
  int* sorted1 = (int*)(ws + 2916352);
  int* sorted2 = (int*)(ws + 3047424);
  int* gbase1  = (int*)(ws + 3178496);
  int* gbase2  = (int*)(ws + 3179520);
  int* cellpre = (int*)(ws + 3180544);
  int* cellcur = (int*)(ws + 3213312);
  float4* pts4 = (float4*)(ws + 3246080);
  float* mur1 = (float*)(ws + 5343232);
  float* mur2 = (float*)(ws + 5343488);
  float* mur3 = (float*)(ws + 5343744);
  float* mm3  = (float*)(ws + 5344768);
  float* Y1g  = (float*)(ws + 7441920);             // 16M
  float* featT = (float*)(ws + 7441920 + 16777216); // 8M (optional)
  size_t NEED_T = (size_t)7441920 + 16777216 + 8388608;
  int useT = (ws_size >= NEED_T) ? 1 : 0;

  hipMemsetAsync(ws + 1179648, 0, 688128, stream);  // hist1,hist2,cellcnt,stats1-3

  prep_kernel<<<512, 256, 0, stream>>>(theta, phi, bits1, bits2, hist1, hist2, cellcnt);
  if (useT)
    transpose_kernel<<<dim3(512, 4), 256, 0, stream>>>(feat, featT);
  scans_kernel<<<6, 256, 0, stream>>>(hist1, hist2, gbase1, gbase2,
                                      cellcnt, cellpre, cellcur);
  bucket_scan_kernel<<<dim3(256, 2), 256, 0, stream>>>(hist1, hist2, gbase1, gbase2,
                                                       prefix1, prefix2, cursor1, cursor2);
  scatter_kernel<<<512, 256, 0, stream>>>(theta, phi, cellcur, pts4,
                                          bits1, bits2, cursor1, cursor2,
                                          sorted1, sorted2);
  rank_scatter1_kernel<<<128, 256, 0, stream>>>(bits1, bits2, prefix1, prefix2,
                                                hist1, hist2, sorted1, sorted2,
                                                xmid, rank2);
  scatter2_kernel<<<128, 256, 0, stream>>>(rank2, xmid, xfin);

  select_kernel<<<1024, 256, 0, stream>>>(theta, phi, xfin, cellpre, cellcnt,
                                          pts4, idx_buf, out_ct, out_cp);

  l1_kernel<<<1024, 256, 0, stream>>>(feat, featT, idx_buf, w0, b0, Y1g, stats1, useT);
  fixup_mur_kernel<32><<<1, 64, 0, stream>>>(stats1, mur1);
  l2_kernel<<<1024, 256, 0, stream>>>(Y1g, mur1, g0, be0, w1, b1, stats2);
  fixup_mur_kernel<32><<<1, 64, 0, stream>>>(stats2, mur2);
  l3_kernel<<<1024, 256, 0, stream>>>(Y1g, mur1, g0, be0, w1, b1,
                                      mur2, g1, be1, w2, b2, mm3, stats3);
  fixup_mur_kernel<64><<<1, 64, 0, stream>>>(stats3, mur3);
  final_small_kernel<<<1024, 256, 0, stream>>>(mm3, mur3, g2, be2, out_ft);
}

// Round 13
// 234.038 us; speedup vs baseline: 1.2323x; 1.1831x over previous
//
#include <hip/hip_runtime.h>
#include <stdint.h>

#define N_PTS 32768
#define M_CENT 1024
#define B_SZ 4
#define NS 32
#define NR 64
#define P_TOT (B_SZ * NS * M_CENT) /* 131072 */

#define GT 29
#define GP 58
#define NCELL (GT * GP) /* 1682 */
#define INVF (1.0f / 0.11f)
#define CAPW 320

__device__ __forceinline__ int cell_t(float t) {
  return min(GT - 1, (int)(t * INVF));
}
__device__ __forceinline__ int cell_p(float p) {
  return min(GP - 1, (int)(p * INVF));
}

// ---------------- threefry2x32 (JAX partitionable mode) ----------------
struct Key2 { uint32_t a, b; };

__device__ __forceinline__ uint32_t rotl32(uint32_t v, uint32_t r) {
  return (v << r) | (v >> (32u - r));
}

__device__ __forceinline__ void tf2x32(uint32_t k0, uint32_t k1,
                                       uint32_t& x0, uint32_t& x1) {
  uint32_t ks0 = k0, ks1 = k1, ks2 = k0 ^ k1 ^ 0x1BD11BDAu;
  x0 += ks0; x1 += ks1;
#define TF_ROUND(r) { x0 += x1; x1 = rotl32(x1, r); x1 ^= x0; }
  TF_ROUND(13u) TF_ROUND(15u) TF_ROUND(26u) TF_ROUND(6u)
  x0 += ks1; x1 += ks2 + 1u;
  TF_ROUND(17u) TF_ROUND(29u) TF_ROUND(16u) TF_ROUND(24u)
  x0 += ks2; x1 += ks0 + 2u;
  TF_ROUND(13u) TF_ROUND(15u) TF_ROUND(26u) TF_ROUND(6u)
  x0 += ks0; x1 += ks1 + 3u;
  TF_ROUND(17u) TF_ROUND(29u) TF_ROUND(16u) TF_ROUND(24u)
  x0 += ks1; x1 += ks2 + 4u;
  TF_ROUND(13u) TF_ROUND(15u) TF_ROUND(26u) TF_ROUND(6u)
  x0 += ks2; x1 += ks0 + 5u;
#undef TF_ROUND
}

__device__ __forceinline__ Key2 tf_block(Key2 k, uint32_t hi, uint32_t lo) {
  uint32_t x0 = hi, x1 = lo;
  tf2x32(k.a, k.b, x0, x1);
  Key2 r; r.a = x0; r.b = x1; return r;
}

// -------- prep: perm bits + bucket hist (j<32768) and cell hist (all j) --------
__global__ __launch_bounds__(256) void prep_kernel(const float* __restrict__ theta,
                                                   const float* __restrict__ phi,
                                                   uint32_t* __restrict__ bits1,
                                                   uint32_t* __restrict__ bits2,
                                                   int* __restrict__ hist1,
                                                   int* __restrict__ hist2,
                                                   int* __restrict__ cellcnt) {
  int j = blockIdx.x * 256 + threadIdx.x;        // 0 .. 131071
  int b = j >> 15;
  float t = theta[j], p = phi[j];
  atomicAdd(&cellcnt[b * NCELL + cell_t(t) * GP + cell_p(p)], 1);
  if (j < N_PTS) {
    Key2 root; root.a = 0u; root.b = 42u;        // jax.random.key(42)
    Key2 k1   = tf_block(root, 0u, 0u);          // split(key)[0] -> permutation key
    Key2 keyA = tf_block(k1, 0u, 0u);
    Key2 sub1 = tf_block(k1, 0u, 1u);
    Key2 sub2 = tf_block(keyA, 0u, 1u);
    Key2 r1 = tf_block(sub1, 0u, (uint32_t)j);
    Key2 r2 = tf_block(sub2, 0u, (uint32_t)j);
    uint32_t v1 = r1.a ^ r1.b, v2 = r2.a ^ r2.b;
    bits1[j] = v1; bits2[j] = v2;
    atomicAdd(&hist1[v1 >> 16], 1);
    atomicAdd(&hist2[v2 >> 16], 1);
  }
}

// -------- feat transpose: [B][16][N] -> [B][N][16] --------
__global__ __launch_bounds__(256) void transpose_kernel(const float* __restrict__ feat,
                                                        float* __restrict__ featT) {
  __shared__ float lds[16][65];
  int b = blockIdx.y;
  int n0 = blockIdx.x * 64;
  int tid = threadIdx.x;
#pragma unroll
  for (int k = 0; k < 4; ++k) {
    int v = tid + k * 256;
    int c = v >> 6, no = v & 63;
    lds[c][no] = feat[((size_t)(b * 16 + c) << 15) + n0 + no];
  }
  __syncthreads();
#pragma unroll
  for (int k = 0; k < 4; ++k) {
    int v = tid + k * 256;
    int no = v >> 4, c = v & 15;
    featT[((size_t)(b << 15) + n0 + no) * 16 + c] = lds[c][no];
  }
}

// -------- fused scans --------
__global__ __launch_bounds__(256) void scans_kernel(const int* __restrict__ hist1,
                                                    const int* __restrict__ hist2,
                                                    int* __restrict__ gbase1,
                                                    int* __restrict__ gbase2,
                                                    const int* __restrict__ cellcnt,
                                                    int* __restrict__ cellpre,
                                                    int* __restrict__ cellcur) {
  __shared__ int s[256];
  int t = threadIdx.x;
  if (blockIdx.x < 2) {
    const int* hist = blockIdx.x == 0 ? hist1 : hist2;
    int* gbase = blockIdx.x == 0 ? gbase1 : gbase2;
    int sum = 0;
    for (int i = 0; i < 256; ++i) sum += hist[t * 256 + i];
    s[t] = sum;
    __syncthreads();
    if (t == 0) {
      int run = 0;
      for (int i = 0; i < 256; ++i) { int v = s[i]; s[i] = run; run += v; }
    }
    __syncthreads();
    gbase[t] = s[t];
  } else {
    int b = blockIdx.x - 2;
    const int* cnt = cellcnt + b * NCELL;
    int i0 = t * 7, i1 = min(i0 + 7, NCELL);
    int sum = 0;
    for (int i = i0; i < i1; ++i) sum += cnt[i];
    s[t] = sum;
    __syncthreads();
    for (int off = 1; off < 256; off <<= 1) {
      int v = (t >= off) ? s[t - off] : 0;
      __syncthreads();
      s[t] += v;
      __syncthreads();
    }
    int run = (t == 0) ? 0 : s[t - 1];
    for (int i = i0; i < i1; ++i) {
      cellpre[b * NCELL + i] = run;
      cellcur[b * NCELL + i] = run;
      run += cnt[i];
    }
  }
}

__global__ __launch_bounds__(256) void bucket_scan_kernel(const int* __restrict__ hist1,
                                                          const int* __restrict__ hist2,
                                                          const int* __restrict__ gbase1,
                                                          const int* __restrict__ gbase2,
                                                          int* __restrict__ prefix1,
                                                          int* __restrict__ prefix2,
                                                          int* __restrict__ cursor1,
                                                          int* __restrict__ cursor2) {
  __shared__ int s[256];
  const int* hist = blockIdx.y == 0 ? hist1 : hist2;
  const int* gbase = blockIdx.y == 0 ? gbase1 : gbase2;
  int* prefix = blockIdx.y == 0 ? prefix1 : prefix2;
  int* cursor = blockIdx.y == 0 ? cursor1 : cursor2;
  int g = blockIdx.x, t = threadIdx.x;
  int idx = g * 256 + t;
  int orig = hist[idx];
  s[t] = orig;
  __syncthreads();
  for (int off = 1; off < 256; off <<= 1) {
    int v = (t >= off) ? s[t - off] : 0;
    __syncthreads();
    s[t] += v;
    __syncthreads();
  }
  int pref = gbase[g] + s[t] - orig;
  prefix[idx] = pref;
  cursor[idx] = pref;
}

// -------- fused scatters --------
__global__ __launch_bounds__(256) void scatter_kernel(const float* __restrict__ theta,
                                                      const float* __restrict__ phi,
                                                      int* __restrict__ cellcur,
                                                      float4* __restrict__ pts4,
                                                      const uint32_t* __restrict__ bits1,
                                                      const uint32_t* __restrict__ bits2,
                                                      int* __restrict__ cursor1,
                                                      int* __restrict__ cursor2,
                                                      int* __restrict__ sorted1,
                                                      int* __restrict__ sorted2) {
  int j = blockIdx.x * 256 + threadIdx.x;
  int b = j >> 15, n = j & (N_PTS - 1);
  float t = theta[j], p = phi[j];
  int cell = b * NCELL + cell_t(t) * GP + cell_p(p);
  int pos = atomicAdd(&cellcur[cell], 1);
  pts4[(b << 15) + pos] = make_float4(t, p, __int_as_float(n), 0.0f);
  if (j < N_PTS) {
    int p1 = atomicAdd(&cursor1[bits1[j] >> 16], 1);
    sorted1[p1] = j;
    int p2 = atomicAdd(&cursor2[bits2[j] >> 16], 1);
    sorted2[p2] = j;
  }
}

__device__ __forceinline__ int exact_rank(const uint32_t* __restrict__ bits,
                                          const int* __restrict__ prefix,
                                          const int* __restrict__ hist,
                                          const int* __restrict__ sorted, int j) {
  uint32_t my = bits[j];
  int b = (int)(my >> 16);
  int start = prefix[b];
  int cnt = hist[b];
  int r = start;
  for (int i = 0; i < cnt; ++i) {
    int m = sorted[start + i];
    uint32_t vb = bits[m];
    if (vb < my || (vb == my && m < j)) ++r;
  }
  return r;
}

__global__ __launch_bounds__(256) void rank_scatter1_kernel(
    const uint32_t* __restrict__ bits1, const uint32_t* __restrict__ bits2,
    const int* __restrict__ prefix1, const int* __restrict__ prefix2,
    const int* __restrict__ hist1, const int* __restrict__ hist2,
    const int* __restrict__ sorted1, const int* __restrict__ sorted2,
    int* __restrict__ xmid, int* __restrict__ rank2) {
  int j = blockIdx.x * 256 + threadIdx.x;
  int r1 = exact_rank(bits1, prefix1, hist1, sorted1, j);
  xmid[r1] = j;
  rank2[j] = exact_rank(bits2, prefix2, hist2, sorted2, j);
}

__global__ __launch_bounds__(256) void scatter2_kernel(const int* __restrict__ rank2,
                                                       const int* __restrict__ xmid,
                                                       int* __restrict__ xfin) {
  int p = blockIdx.x * 256 + threadIdx.x;
  xfin[rank2[p]] = xmid[p];
}

// -------- neighbor selection: one WAVE per center (4 waves/block) --------
__global__ __launch_bounds__(256) void select_kernel(
    const float* __restrict__ theta, const float* __restrict__ phi,
    const int* __restrict__ cent,
    const int* __restrict__ cellpre, const int* __restrict__ cellcnt,
    const float4* __restrict__ pts4,
    int* __restrict__ idx_buf, float* __restrict__ out_ct, float* __restrict__ out_cp) {
  __shared__ float wsc[4][CAPW];
  __shared__ int wsn[4][CAPW];
  int tid = threadIdx.x;
  int w = tid >> 6, lane = tid & 63;
  int bm = blockIdx.x * 4 + w;
  int b = bm >> 10, m = bm & 1023;
  int ci = cent[m];
  float ctv = theta[(b << 15) + ci];
  float cpv = phi[(b << 15) + ci];
  if (lane == 0) { out_ct[bm] = ctv; out_cp[bm] = cpv; }

  Key2 root; root.a = 0u; root.b = 42u;
  Key2 k2 = tf_block(root, 0u, 1u);              // split(key)[1] -> scores key
  uint32_t flat_base = (uint32_t)bm << 15;

  int tc = cell_t(ctv), pc = cell_p(cpv);
  int t0 = max(0, tc - 1), t1 = min(GT - 1, tc + 1);
  int p0 = max(0, pc - 1), p1 = min(GP - 1, pc + 1);
  int nct = t1 - t0 + 1, ncp = p1 - p0 + 1, ncells = nct * ncp;

  int cst = 0, ccn = 0;
  if (lane < ncells) {
    int cell = b * NCELL + (t0 + lane / ncp) * GP + (p0 + lane % ncp);
    cst = cellpre[cell];
    ccn = cellcnt[cell];
  }
  int sc9[9], cc9[9];
#pragma unroll
  for (int k = 0; k < 9; ++k) {
    sc9[k] = __shfl(cst, k);
    cc9[k] = __shfl(ccn, k);
  }
  int T = 0;
#pragma unroll
  for (int k = 0; k < 9; ++k) T += cc9[k];

  const float4* bpts = pts4 + ((size_t)b << 15);
  int wcnt = 0;
  for (int base = 0; base < T; base += 64) {
    int i = base + lane;
    bool hit = false; float sc = 0.0f; int n = 0;
    if (i < T) {
      int gidx = 0, acc = 0;
#pragma unroll
      for (int k = 0; k < 9; ++k) {
        int lo = acc; acc += cc9[k];
        if (i >= lo && i < acc) gidx = sc9[k] + (i - lo);
      }
      float4 pt = bpts[gidx];
      float dx = __fsub_rn(pt.x, ctv);
      float dy = __fsub_rn(pt.y, cpv);
      float d = __fsqrt_rn(__fadd_rn(__fmul_rn(dx, dx), __fmul_rn(dy, dy)));
      if (d <= 0.1f) {
        hit = true; n = __float_as_int(pt.z);
        Key2 r = tf_block(k2, 0u, flat_base + (uint32_t)n);
        uint32_t bits = r.a ^ r.b;
        sc = __uint_as_float(0x3f800000u | (bits >> 9)) - 1.0f; // uniform [0,1)
      }
    }
    unsigned long long mask = __ballot(hit);
    int pos = wcnt + __popcll(mask & ((1ull << lane) - 1ull));
    if (hit && pos < CAPW) { wsc[w][pos] = sc; wsn[w][pos] = n; }
    wcnt = min(wcnt + (int)__popcll(mask), CAPW);
  }

  int mysel;
  if (wcnt <= 64) {
    float s = (lane < wcnt) ? wsc[w][lane] : 3.0e38f;
    int n = (lane < wcnt) ? wsn[w][lane] : 0x7fffffff;
#pragma unroll
    for (int k = 2; k <= 64; k <<= 1) {
#pragma unroll
      for (int jj = k >> 1; jj > 0; jj >>= 1) {
        float os = __shfl_xor(s, jj);
        int on = __shfl_xor(n, jj);
        bool lower = (lane & jj) == 0;
        bool dir = (lane & k) == 0;
        bool mineFirst = (s < os) || (s == os && n < on);
        bool takeMine = ((lower == mineFirst) == dir);
        s = takeMine ? s : os;
        n = takeMine ? n : on;
      }
    }
    int n0 = __shfl(n, 0);
    mysel = (lane < wcnt) ? n : n0;
  } else {
    float ls = -1.0f; int ln = -1;
    int sel0 = -1; mysel = -1;
    for (int r = 0; r < NS; ++r) {
      float best = 3.0e38f; int bn = 0x7fffffff;
      for (int i = lane; i < wcnt; i += 64) {
        float s = wsc[w][i]; int n = wsn[w][i];
        bool after = (s > ls) || (s == ls && n > ln);
        bool better = (s < best) || (s == best && n < bn);
        if (after && better) { best = s; bn = n; }
      }
      for (int off = 32; off; off >>= 1) {
        float os = __shfl_xor(best, off);
        int on = __shfl_xor(bn, off);
        if (os < best || (os == best && on < bn)) { best = os; bn = on; }
      }
      int chosen;
      if (best < 3.0e38f) { ls = best; ln = bn; chosen = bn; }
      else chosen = sel0;
      if (r == 0) sel0 = chosen;
      if (lane == r) mysel = chosen;
    }
  }
  if (lane < NS) idx_buf[bm * NS + lane] = mysel;
}

// -------- MLP: register-FMA with SGPR weights (readfirstlane) --------
__device__ __forceinline__ float bn_relu(float y, float mu, float r, float g, float be) {
  float t = __fsub_rn(y, mu);
  t = __fmul_rn(t, r);
  t = __fmul_rn(t, g);
  t = __fadd_rn(t, be);
  return fmaxf(t, 0.0f);
}

// compute mu/rsqrt pair for CO channels from stats (layout: rep*(2*CO), [o],[CO+o])
template <int CO>
__device__ __forceinline__ void mur_from_stats(const double* __restrict__ S,
                                               float* murs, int tid) {
  if (tid < CO) {
    double s1 = 0.0, s2 = 0.0;
    for (int r = 0; r < NR; ++r) {
      s1 += S[r * 2 * CO + tid];
      s2 += S[r * 2 * CO + CO + tid];
    }
    const double P = (double)P_TOT;
    double mu = s1 / P;
    double var = s2 / P - mu * mu;
    murs[tid] = (float)mu;
    murs[CO + tid] = (float)(1.0 / sqrt(var + 1e-5));
  }
}

// L1: block = 128 positions x 2 halves. h (SGPR) computes 16 of 32 outputs.
__global__ __launch_bounds__(256) void l1_kernel(
    const float* __restrict__ feat, const float* __restrict__ featT,
    const int* __restrict__ idx_buf,
    const float* __restrict__ w0, const float* __restrict__ b0,
    float* __restrict__ Y1g, double* __restrict__ stats, int useT) {
  __shared__ float y1s[128 * 34];
  int tid = threadIdx.x;
  int pl = tid & 127;
  int h = __builtin_amdgcn_readfirstlane(tid >> 7);   // wave-uniform -> SGPR
  int pg = blockIdx.x * 128 + pl;
  int bm = pg >> 5, s = pg & 31, b = bm >> 10;
  int idx = idx_buf[pg];
  float x[16];
  if (useT) {
    const float4* src = reinterpret_cast<const float4*>(
        featT + (((size_t)b << 15) + (size_t)idx) * 16);
#pragma unroll
    for (int q = 0; q < 4; ++q) {
      float4 f = src[q];
      x[q * 4 + 0] = f.x; x[q * 4 + 1] = f.y;
      x[q * 4 + 2] = f.z; x[q * 4 + 3] = f.w;
    }
  } else {
#pragma unroll
    for (int c = 0; c < 16; ++c)
      x[c] = feat[((size_t)(b * 16 + c) << 15) + idx];
  }
#pragma unroll
  for (int oo = 0; oo < 16; ++oo) {
    int o = h * 16 + oo;                              // uniform -> s_load row
    float acc = b0[o];
    const float* wr = w0 + o * 16;
#pragma unroll
    for (int c = 0; c < 16; ++c) acc = fmaf(wr[c], x[c], acc);
    Y1g[(size_t)bm * 1024 + o * 32 + s] = acc;
    y1s[pl * 34 + o] = acc;
  }
  __syncthreads();
  int ch = tid & 31, seg = tid >> 5;
  float s1 = 0.0f, s2 = 0.0f;
#pragma unroll
  for (int i = 0; i < 16; ++i) {
    float v = y1s[(seg * 16 + i) * 34 + ch];
    s1 += v; s2 += v * v;
  }
  double* base = stats + (size_t)(blockIdx.x & (NR - 1)) * 64;
  atomicAdd(base + ch, (double)s1);
  atomicAdd(base + 32 + ch, (double)s2);
}

// L2: inline mur1 from stats1; stats2 only.
__global__ __launch_bounds__(256) void l2_kernel(
    const float* __restrict__ Y1g, const double* __restrict__ stats1,
    const float* __restrict__ g0, const float* __restrict__ be0,
    const float* __restrict__ w1, const float* __restrict__ b1,
    double* __restrict__ stats) {
  __shared__ float y2s[128 * 34];
  __shared__ float m1s[64];
  int tid = threadIdx.x;
  mur_from_stats<32>(stats1, m1s, tid);
  __syncthreads();
  int pl = tid & 127;
  int h = __builtin_amdgcn_readfirstlane(tid >> 7);
  int pg = blockIdx.x * 128 + pl;
  int bm = pg >> 5, s = pg & 31;
  float x2[32];
#pragma unroll
  for (int c = 0; c < 32; ++c)
    x2[c] = bn_relu(Y1g[(size_t)bm * 1024 + c * 32 + s],
                    m1s[c], m1s[32 + c], g0[c], be0[c]);
#pragma unroll
  for (int oo = 0; oo < 16; ++oo) {
    int o = h * 16 + oo;
    float acc = b1[o];
    const float* wr = w1 + o * 32;
#pragma unroll
    for (int c = 0; c < 32; ++c) acc = fmaf(wr[c], x2[c], acc);
    y2s[pl * 34 + o] = acc;
  }
  __syncthreads();
  int ch = tid & 31, seg = tid >> 5;
  float s1 = 0.0f, s2 = 0.0f;
#pragma unroll
  for (int i = 0; i < 16; ++i) {
    float v = y2s[(seg * 16 + i) * 34 + ch];
    s1 += v; s2 += v * v;
  }
  double* base = stats + (size_t)(blockIdx.x & (NR - 1)) * 64;
  atomicAdd(base + ch, (double)s1);
  atomicAdd(base + 32 + ch, (double)s2);
}

// L3: inline mur1+mur2; h (SGPR) computes x3-half then 32 of 64 outputs.
__global__ __launch_bounds__(256) void l3_kernel(
    const float* __restrict__ Y1g,
    const double* __restrict__ stats1, const double* __restrict__ stats2,
    const float* __restrict__ g0, const float* __restrict__ be0,
    const float* __restrict__ w1, const float* __restrict__ b1,
    const float* __restrict__ g1, const float* __restrict__ be1,
    const float* __restrict__ w2, const float* __restrict__ b2,
    float* __restrict__ mm3, double* __restrict__ stats) {
  __shared__ float smem[128 * 66];
  __shared__ float m1s[64];
  __shared__ float m2s[64];
  int tid = threadIdx.x;
  mur_from_stats<32>(stats1, m1s, tid);
  if (tid >= 64 && tid < 96) mur_from_stats<32>(stats2, m2s, tid - 64);
  __syncthreads();
  int pl = tid & 127;
  int h = __builtin_amdgcn_readfirstlane(tid >> 7);
  int pg = blockIdx.x * 128 + pl;
  int bm = pg >> 5, s = pg & 31;
  float x2[32];
#pragma unroll
  for (int c = 0; c < 32; ++c)
    x2[c] = bn_relu(Y1g[(size_t)bm * 1024 + c * 32 + s],
                    m1s[c], m1s[32 + c], g0[c], be0[c]);
  // x3 half -> LDS
#pragma unroll
  for (int cc = 0; cc < 16; ++cc) {
    int c = h * 16 + cc;
    float acc = b1[c];
    const float* wr = w1 + c * 32;
#pragma unroll
    for (int k = 0; k < 32; ++k) acc = fmaf(wr[k], x2[k], acc);
    smem[pl * 34 + c] = bn_relu(acc, m2s[c], m2s[32 + c], g1[c], be1[c]);
  }
  __syncthreads();
  float x3[32];
#pragma unroll
  for (int c = 0; c < 32; ++c) x3[c] = smem[pl * 34 + c];
  __syncthreads();
#pragma unroll
  for (int oo = 0; oo < 32; ++oo) {
    int o = h * 32 + oo;
    float acc = b2[o];
    const float* wr = w2 + o * 32;
#pragma unroll
    for (int c = 0; c < 32; ++c) acc = fmaf(wr[c], x3[c], acc);
    smem[pl * 66 + o] = acc;
  }
  __syncthreads();
  int ch = tid & 63, bmq = tid >> 6;
  float s1 = 0.0f, s2 = 0.0f, mx = -3.0e38f, mn = 3.0e38f;
#pragma unroll
  for (int i = 0; i < 32; ++i) {
    float v = smem[(bmq * 32 + i) * 66 + ch];
    s1 += v; s2 += v * v;
    mx = fmaxf(mx, v); mn = fminf(mn, v);
  }
  double* base = stats + (size_t)(blockIdx.x & (NR - 1)) * 128;
  atomicAdd(base + ch, (double)s1);
  atomicAdd(base + 64 + ch, (double)s2);
  int bmg = blockIdx.x * 4 + bmq;
  mm3[bmg * 128 + ch * 2] = mx;
  mm3[bmg * 128 + ch * 2 + 1] = mn;
}

// final: inline mur3; BN3 on extremum (exact: bn_relu weakly monotone in y)
__global__ __launch_bounds__(256) void final_small_kernel(
    const float* __restrict__ mm3, const double* __restrict__ stats3,
    const float* __restrict__ g2, const float* __restrict__ be2,
    float* __restrict__ out_ft) {
  __shared__ float m3s[128];
  int tid = threadIdx.x;
  mur_from_stats<64>(stats3, m3s, tid);
  __syncthreads();
  int j = blockIdx.x * 256 + tid;                  // (b*64+o)*1024+m
  int b = j >> 16, o = (j >> 10) & 63, m = j & 1023;
  int bm = b * 1024 + m;
  float g = g2[o];
  float y = (g >= 0.0f) ? mm3[bm * 128 + o * 2] : mm3[bm * 128 + o * 2 + 1];
  out_ft[j] = bn_relu(y, m3s[o], m3s[64 + o], g, be2[o]);
}

extern "C" void kernel_launch(void* const* d_in, const int* in_sizes, int n_in,
                              void* d_out, int out_size, void* d_ws, size_t ws_size,
                              hipStream_t stream) {
  (void)in_sizes; (void)n_in; (void)out_size;
  const float* theta = (const float*)d_in[0];
  const float* phi   = (const float*)d_in[1];
  const float* feat  = (const float*)d_in[2];
  const float* w0 = (const float*)d_in[3];
  const float* b0 = (const float*)d_in[4];
  const float* g0 = (const float*)d_in[5];
  const float* be0 = (const float*)d_in[6];
  const float* w1 = (const float*)d_in[7];
  const float* b1 = (const float*)d_in[8];
  const float* g1 = (const float*)d_in[9];
  const float* be1 = (const float*)d_in[10];
  const float* w2 = (const float*)d_in[11];
  const float* b2 = (const float*)d_in[12];
  const float* g2 = (const float*)d_in[13];
  const float* be2 = (const float*)d_in[14];

  float* out = (float*)d_out;
  float* out_ct = out;
  float* out_cp = out + B_SZ * M_CENT;
  float* out_ft = out + 2 * B_SZ * M_CENT;

  char* ws = (char*)d_ws;
  uint32_t* bits1 = (uint32_t*)(ws + 0);
  uint32_t* bits2 = (uint32_t*)(ws + 131072);
  int* rank2 = (int*)(ws + 262144);
  int* xmid  = (int*)(ws + 393216);
  int* xfin  = (int*)(ws + 524288);      // xfin[0:1024] == cent_idx
  int* idx_buf = (int*)(ws + 655360);
  int* hist1   = (int*)(ws + 1179648);
  int* hist2   = (int*)(ws + 1441792);
  int* cellcnt = (int*)(ws + 1703936);
  double* stats1 = (double*)(ws + 1736704);
  double* stats2 = (double*)(ws + 1769472);
  double* stats3 = (double*)(ws + 1802240);
  int* prefix1 = (int*)(ws + 1867776);
  int* prefix2 = (int*)(ws + 2129920);
  int* cursor1 = (int*)(ws + 2392064);
  int* cursor2 = (int*)(ws + 2654208);
  int* sorted1 = (int*)(ws + 2916352);
  int* sorted2 = (int*)(ws + 3047424);
  int* gbase1  = (int*)(ws + 3178496);
  int* gbase2  = (int*)(ws + 3179520);
  int* cellpre = (int*)(ws + 3180544);
  int* cellcur = (int*)(ws + 3213312);
  float4* pts4 = (float4*)(ws + 3246080);
  float* mm3  = (float*)(ws + 5344768);
  float* Y1g  = (float*)(ws + 7441920);             // 16M
  float* featT = (float*)(ws + 7441920 + 16777216); // 8M (optional)
  size_t NEED_T = (size_t)7441920 + 16777216 + 8388608;
  int useT = (ws_size >= NEED_T) ? 1 : 0;

  hipMemsetAsync(ws + 1179648, 0, 688128, stream);  // hist1,hist2,cellcnt,stats1-3

  prep_kernel<<<512, 256, 0, stream>>>(theta, phi, bits1, bits2, hist1, hist2, cellcnt);
  if (useT)
    transpose_kernel<<<dim3(512, 4), 256, 0, stream>>>(feat, featT);
  scans_kernel<<<6, 256, 0, stream>>>(hist1, hist2, gbase1, gbase2,
                                      cellcnt, cellpre, cellcur);
  bucket_scan_kernel<<<dim3(256, 2), 256, 0, stream>>>(hist1, hist2, gbase1, gbase2,
                                                       prefix1, prefix2, cursor1, cursor2);
  scatter_kernel<<<512, 256, 0, stream>>>(theta, phi, cellcur, pts4,
                                          bits1, bits2, cursor1, cursor2,
                                          sorted1, sorted2);
  rank_scatter1_kernel<<<128, 256, 0, stream>>>(bits1, bits2, prefix1, prefix2,
                                                hist1, hist2, sorted1, sorted2,
                                                xmid, rank2);
  scatter2_kernel<<<128, 256, 0, stream>>>(rank2, xmid, xfin);

  select_kernel<<<1024, 256, 0, stream>>>(theta, phi, xfin, cellpre, cellcnt,
                                          pts4, idx_buf, out_ct, out_cp);

  l1_kernel<<<1024, 256, 0, stream>>>(feat, featT, idx_buf, w0, b0, Y1g, stats1, useT);
  l2_kernel<<<1024, 256, 0, stream>>>(Y1g, stats1, g0, be0, w1, b1, stats2);
  l3_kernel<<<1024, 256, 0, stream>>>(Y1g, stats1, stats2, g0, be0, w1, b1,
                                      g1, be1, w2, b2, mm3, stats3);
  final_small_kernel<<<1024, 256, 0, stream>>>(mm3, stats3, g2, be2, out_ft);
}